// Round 1
// 132.174 us; speedup vs baseline: 1.0699x; 1.0699x over previous
//
#include <hip/hip_runtime.h>
#include <math.h>

#define N 4096
#define IN_F 256
#define OUT_F 64
#define HEADS 4
#define NEG 0.2f
#define JLEN 512                 // j-slice per wave
#define NC (JLEN / 32)           // 16 chunks per wave
#define LOG2E 1.44269504088896f
#define RSTR 68                  // reduce-buffer row stride (floats): 64 O + 1 l + pad

typedef float f32x4 __attribute__((ext_vector_type(4)));
typedef float f32x2 __attribute__((ext_vector_type(2)));
typedef short short8 __attribute__((ext_vector_type(8)));

#define FMA4S(A, s, V) do { (A).x = fmaf((s),(V).x,(A).x); (A).y = fmaf((s),(V).y,(A).y); \
                            (A).z = fmaf((s),(V).z,(A).z); (A).w = fmaf((s),(V).w,(A).w); } while(0)

// zero P unless bit R of MS is set: AND float bits with sign-extended bit
#define MSEL(P, MS, R) (P) = __uint_as_float(__float_as_uint(P) & \
                         (unsigned)(((int)((MS) << (31 - (R)))) >> 31))

__device__ __forceinline__ unsigned short f2bf(float x) {
  unsigned int u = __float_as_uint(x);
  u += 0x7fffu + ((u >> 16) & 1u);   // RNE
  return (unsigned short)(u >> 16);
}

__device__ __forceinline__ float exp2_fast(float x) {
#if __has_builtin(__builtin_amdgcn_exp2f)
  return __builtin_amdgcn_exp2f(x);
#else
  return exp2f(x);
#endif
}

// pack bf16(p1)<<16 | bf16(p0), round-half-up
__device__ __forceinline__ int pack_bf2(float p0, float p1) {
  unsigned u0 = __float_as_uint(p0) + 0x8000u;
  unsigned u1 = __float_as_uint(p1) + 0x8000u;
  return (int)__builtin_amdgcn_perm(u1, u0, 0x07060302u);
}

// ---------------------------------------------------------------------------
// Kernel 1: fused prep. Blocks [0,512): xt = x @ W[h] (32-row tile, LDS-staged)
// -> src/dst (log2e-scaled) + xtB (bf16 B-frag). Blocks [512,8704): adj ->
// bitmask stream. Data-independent partitions overlap HBM stream with GEMM.
// NOTE (R12 lesson): do NOT fuse across kernels with device fences —
// agent-scope __threadfence() per block causes a cross-XCD L2
// writeback/invalidate storm (172 µs vs 28 µs). Kernel boundary is cheaper.
// ---------------------------------------------------------------------------
__global__ __launch_bounds__(256) void k_prep(const float* __restrict__ x,
                                              const float* __restrict__ W,
                                              const float* __restrict__ a,
                                              const int* __restrict__ adj,
                                              short* __restrict__ xtB,
                                              float* __restrict__ src,
                                              float* __restrict__ dst,
                                              unsigned char* __restrict__ mbB) {
  __shared__ __align__(16) float xls[32 * 68];
  __shared__ __align__(16) float wls[64 * 64];
  const int t = threadIdx.x;

  if (blockIdx.x >= 512) {
    int tid = (blockIdx.x - 512) * 256 + t;
    const int4* a4 = (const int4*)adj + (size_t)tid * 2;
    int4 v0 = a4[0];
    int4 v1 = a4[1];
    unsigned b = 0;
    b |= (v0.x > 0) ? 0x01u : 0u;
    b |= (v0.y > 0) ? 0x02u : 0u;
    b |= (v0.z > 0) ? 0x04u : 0u;
    b |= (v0.w > 0) ? 0x08u : 0u;
    b |= (v1.x > 0) ? 0x10u : 0u;
    b |= (v1.y > 0) ? 0x20u : 0u;
    b |= (v1.z > 0) ? 0x40u : 0u;
    b |= (v1.w > 0) ? 0x80u : 0u;
    mbB[tid] = (unsigned char)b;
    return;
  }

  const int h  = blockIdx.x >> 7;
  const int bx = blockIdx.x & 127;
  const int i0 = bx * 32;
  const int fg = t & 15;
  const int rg = t >> 4;

  float4 acc[2];
  acc[0] = acc[1] = make_float4(0.f, 0.f, 0.f, 0.f);

  const float4* xg = (const float4*)x;
  const float4* wg = (const float4*)W;
  float4* xls4 = (float4*)xls;
  float4* wls4 = (float4*)wls;
  const float4* xr4 = (const float4*)xls;
  const float4* wr4 = (const float4*)wls;

  for (int kt = 0; kt < 4; ++kt) {
    __syncthreads();
    #pragma unroll
    for (int s = 0; s < 2; ++s) {
      int f4i = t + 256 * s;
      int row = f4i >> 4, c4 = f4i & 15;
      xls4[row * 17 + c4] = xg[(size_t)(i0 + row) * 64 + kt * 16 + c4];
    }
    #pragma unroll
    for (int s = 0; s < 4; ++s) {
      int f4i = t + 256 * s;
      int kk = f4i >> 4, c4 = f4i & 15;
      wls4[kk * 16 + c4] = wg[(size_t)(h * 256 + kt * 64 + kk) * 16 + c4];
    }
    __syncthreads();
    #pragma unroll 4
    for (int kk = 0; kk < 64; kk += 4) {
      float4 wv0 = wr4[(kk + 0) * 16 + fg];
      float4 wv1 = wr4[(kk + 1) * 16 + fg];
      float4 wv2 = wr4[(kk + 2) * 16 + fg];
      float4 wv3 = wr4[(kk + 3) * 16 + fg];
      #pragma unroll
      for (int q = 0; q < 2; ++q) {
        float4 xv = xr4[(rg * 2 + q) * 17 + (kk >> 2)];
        FMA4S(acc[q], xv.x, wv0);
        FMA4S(acc[q], xv.y, wv1);
        FMA4S(acc[q], xv.z, wv2);
        FMA4S(acc[q], xv.w, wv3);
      }
    }
  }

  const float4* a4 = (const float4*)a;
  float4 as = a4[h * 32 + fg];
  float4 ad = a4[h * 32 + 16 + fg];
  as.x *= LOG2E; as.y *= LOG2E; as.z *= LOG2E; as.w *= LOG2E;
  ad.x *= LOG2E; ad.y *= LOG2E; ad.z *= LOG2E; ad.w *= LOG2E;
  #pragma unroll
  for (int q = 0; q < 2; ++q) {
    float s_ = acc[q].x * as.x + acc[q].y * as.y + acc[q].z * as.z + acc[q].w * as.w;
    float d_ = acc[q].x * ad.x + acc[q].y * ad.y + acc[q].z * ad.z + acc[q].w * ad.w;
    #pragma unroll
    for (int off = 1; off < 16; off <<= 1) {
      s_ += __shfl_xor(s_, off, 64);
      d_ += __shfl_xor(d_, off, 64);
    }
    if (fg == 0) {
      int r = rg * 2 + q;
      src[h * N + i0 + r] = s_;
      dst[h * N + i0 + r] = d_;
    }
  }

  __syncthreads();
  #pragma unroll
  for (int q = 0; q < 2; ++q) {
    *(float4*)&xls[(rg * 2 + q) * 68 + fg * 4] = acc[q];
  }
  __syncthreads();

  {
    const int lane = t & 63;
    const int g    = t >> 6;
    const int q    = lane >> 4;
    const int m    = lane & 15;
    short8 bv;
    #pragma unroll
    for (int r = 0; r < 8; ++r) {
      bv[r] = (short)f2bf(xls[(q * 8 + r) * 68 + g * 16 + m]);
    }
    ((short8*)xtB)[((size_t)(h * 128 + bx) * 4 + g) * 64 + lane] = bv;
  }
}

// ---------------------------------------------------------------------------
// Kernel 2: fused flash PV + in-block j-reduction. grid (128, HEADS), block
// 512 = 8 waves. Each wave runs the old 16-chunk inner loop on its own 512-j
// slice (same per-wave work/occupancy as before: 16 waves/CU); the 8 fp32
// partial-O/l sets are tree-reduced in LDS (3 rounds) and the FINAL
// normalized output is written directly. accPu / lP / k_div are gone:
// saves ~34 MB HBM round-trip + one launch, and removes the bf16 rounding
// of partials (fp32 accumulate end-to-end, single final rounding).
// ---------------------------------------------------------------------------
__global__ __launch_bounds__(512) void k_flash(const unsigned* __restrict__ mb,
                                               const float* __restrict__ src,
                                               const float* __restrict__ dst,
                                               const short* __restrict__ xtB,
                                               float* __restrict__ out) {
  // 4 reduce slots x 32 rows x RSTR floats = 34.8 KB.
  // First 4096 floats double as the dst[h] cache during the j-loop.
  __shared__ __align__(16) float smem[4 * 32 * RSTR];
  const int t    = threadIdx.x;
  const int lane = t & 63;
  const int w    = t >> 6;            // wave id = j-slice id
  const int h    = blockIdx.y;
  const int i0   = blockIdx.x * 32;
  const int q    = lane >> 4;
  const int m    = lane & 15;
  const int koff = q * 8;
  const int jbase = w * JLEN;

  // stage full dst row for this head: 4096 floats
  {
    const float4* dg = (const float4*)(dst + (size_t)h * N);
    float4* ds4 = (float4*)smem;
    ds4[t]       = dg[t];
    ds4[t + 512] = dg[t + 512];
  }

  float sv = (lane < 32) ? src[h * N + i0 + lane] : 0.f;
  const float s0 = __shfl(sv, m, 64);
  const float s1 = __shfl(sv, 16 + m, 64);
  __syncthreads();

  f32x4 acc0[4], acc1[4], accL0, accL1;
  #pragma unroll
  for (int g = 0; g < 4; ++g) { acc0[g] = (f32x4)(0.f); acc1[g] = (f32x4)(0.f); }
  accL0 = (f32x4)(0.f);
  accL1 = (f32x4)(0.f);

  short8 ones;
  #pragma unroll
  for (int r = 0; r < 8; ++r) ones[r] = (short)0x3F80;

  const f32x2 s02 = (f32x2)(s0);
  const f32x2 s12 = (f32x2)(s1);

  const unsigned* mrow0 = mb + (size_t)(i0 + m) * 128 + w * NC;
  const unsigned* mrow1 = mb + (size_t)(i0 + 16 + m) * 128 + w * NC;
  const short8* xbb = (const short8*)xtB + ((size_t)(h * 128 + w * NC) * 4) * 64 + lane;

#define LOADC(DM0, DM1, DB, CIDX) do {                                     \
    DM0 = mrow0[CIDX];                                                     \
    DM1 = mrow1[CIDX];                                                     \
    const short8* bb_ = xbb + (size_t)(CIDX) * 256;                        \
    DB[0] = bb_[0]; DB[1] = bb_[64]; DB[2] = bb_[128]; DB[3] = bb_[192];   \
  } while (0)

#define COMPUTE(CM0, CM1, CB, C) do {                                      \
    const float* dp_ = &smem[jbase + (C) * 32 + koff];                     \
    union { float4 v[2]; f32x2 h2[4]; float f[8]; } du;                    \
    du.v[0] = *(const float4*)dp_;                                         \
    du.v[1] = *(const float4*)(dp_ + 4);                                   \
    unsigned ms0 = (CM0) >> koff;                                          \
    unsigned ms1 = (CM1) >> koff;                                          \
    int av0[4], av1[4];                                                    \
    _Pragma("unroll")                                                      \
    for (int r2 = 0; r2 < 4; ++r2) {                                       \
      f32x2 d2 = du.h2[r2];                                                \
      f32x2 e0 = s02 + d2;                                                 \
      f32x2 el0 = __builtin_elementwise_max(e0, e0 * NEG);                 \
      f32x2 e1 = s12 + d2;                                                 \
      f32x2 el1 = __builtin_elementwise_max(e1, e1 * NEG);                 \
      float p0a = exp2_fast(el0.x), p0b = exp2_fast(el0.y);                \
      float p1a = exp2_fast(el1.x), p1b = exp2_fast(el1.y);                \
      MSEL(p0a, ms0, 2 * r2);  MSEL(p0b, ms0, 2 * r2 + 1);                 \
      MSEL(p1a, ms1, 2 * r2);  MSEL(p1b, ms1, 2 * r2 + 1);                 \
      av0[r2] = pack_bf2(p0a, p0b);                                        \
      av1[r2] = pack_bf2(p1a, p1b);                                        \
    }                                                                      \
    short8 af0 = __builtin_bit_cast(short8, *(int4*)av0);                  \
    short8 af1 = __builtin_bit_cast(short8, *(int4*)av1);                  \
    acc0[0] = __builtin_amdgcn_mfma_f32_16x16x32_bf16(af0, CB[0], acc0[0], 0, 0, 0); \
    acc0[1] = __builtin_amdgcn_mfma_f32_16x16x32_bf16(af0, CB[1], acc0[1], 0, 0, 0); \
    acc0[2] = __builtin_amdgcn_mfma_f32_16x16x32_bf16(af0, CB[2], acc0[2], 0, 0, 0); \
    acc0[3] = __builtin_amdgcn_mfma_f32_16x16x32_bf16(af0, CB[3], acc0[3], 0, 0, 0); \
    accL0   = __builtin_amdgcn_mfma_f32_16x16x32_bf16(af0, ones,  accL0,   0, 0, 0); \
    acc1[0] = __builtin_amdgcn_mfma_f32_16x16x32_bf16(af1, CB[0], acc1[0], 0, 0, 0); \
    acc1[1] = __builtin_amdgcn_mfma_f32_16x16x32_bf16(af1, CB[1], acc1[1], 0, 0, 0); \
    acc1[2] = __builtin_amdgcn_mfma_f32_16x16x32_bf16(af1, CB[2], acc1[2], 0, 0, 0); \
    acc1[3] = __builtin_amdgcn_mfma_f32_16x16x32_bf16(af1, CB[3], acc1[3], 0, 0, 0); \
    accL1   = __builtin_amdgcn_mfma_f32_16x16x32_bf16(af1, ones,  accL1,   0, 0, 0); \
  } while (0)

  unsigned cM0, cM1, nM0, nM1;
  short8 cB[4], nB[4];
  LOADC(cM0, cM1, cB, 0);

  for (int c = 0; c < NC; ++c) {
    const int cn = (c + 1 < NC) ? c + 1 : c;
    LOADC(nM0, nM1, nB, cn);

    COMPUTE(cM0, cM1, cB, c);

    cM0 = nM0; cM1 = nM1;
    #pragma unroll
    for (int z = 0; z < 4; ++z) cB[z] = nB[z];
  }
#undef LOADC
#undef COMPUTE

  // ---- in-block tree reduction of 8 wave partials (fp32) ----------------
  // row layout per slot: [row 0..31][RSTR floats: 64 O-cols + l at col 64]
  // store/add addr = row*68 + col -> worst 2-way bank alias (free, m136).
#define RED_ST(SLOT) do {                                                  \
    float* part_ = smem + (SLOT) * (32 * RSTR);                            \
    _Pragma("unroll")                                                      \
    for (int g = 0; g < 4; ++g)                                            \
      _Pragma("unroll")                                                    \
      for (int rr = 0; rr < 4; ++rr) {                                     \
        part_[(q * 4 + rr) * RSTR + g * 16 + m]      = acc0[g][rr];        \
        part_[(q * 4 + rr + 16) * RSTR + g * 16 + m] = acc1[g][rr];        \
      }                                                                    \
    if (m == 0) {                                                          \
      _Pragma("unroll")                                                    \
      for (int rr = 0; rr < 4; ++rr) {                                     \
        part_[(q * 4 + rr) * RSTR + 64]      = accL0[rr];                  \
        part_[(q * 4 + rr + 16) * RSTR + 64] = accL1[rr];                  \
      }                                                                    \
    }                                                                      \
  } while (0)
#define RED_ADD(SLOT) do {                                                 \
    const float* part_ = smem + (SLOT) * (32 * RSTR);                      \
    _Pragma("unroll")                                                      \
    for (int g = 0; g < 4; ++g)                                            \
      _Pragma("unroll")                                                    \
      for (int rr = 0; rr < 4; ++rr) {                                     \
        acc0[g][rr] += part_[(q * 4 + rr) * RSTR + g * 16 + m];            \
        acc1[g][rr] += part_[(q * 4 + rr + 16) * RSTR + g * 16 + m];       \
      }                                                                    \
    _Pragma("unroll")                                                      \
    for (int rr = 0; rr < 4; ++rr) {                                       \
      accL0[rr] += part_[(q * 4 + rr) * RSTR + 64];                        \
      accL1[rr] += part_[(q * 4 + rr + 16) * RSTR + 64];                   \
    }                                                                      \
  } while (0)

  __syncthreads();                    // j-loop done; dls region now dead
  if (w >= 4) RED_ST(w - 4);          // slots 0..3 <- waves 4..7
  __syncthreads();
  if (w < 4) RED_ADD(w);              // waves 0..3 hold pairwise sums
  __syncthreads();
  if (w == 2 || w == 3) RED_ST(w - 2);
  __syncthreads();
  if (w < 2) RED_ADD(w);              // waves 0,1 hold 4-way sums
  __syncthreads();
  if (w == 0) RED_ST(0);
  __syncthreads();
  if (w == 1) {                       // rmw: slot 0 += wave1 -> final
    float* part_ = smem;
    #pragma unroll
    for (int g = 0; g < 4; ++g)
      #pragma unroll
      for (int rr = 0; rr < 4; ++rr) {
        part_[(q * 4 + rr) * RSTR + g * 16 + m]      += acc0[g][rr];
        part_[(q * 4 + rr + 16) * RSTR + g * 16 + m] += acc1[g][rr];
      }
    if (m == 0) {
      #pragma unroll
      for (int rr = 0; rr < 4; ++rr) {
        part_[(q * 4 + rr) * RSTR + 64]      += accL0[rr];
        part_[(q * 4 + rr + 16) * RSTR + 64] += accL1[rr];
      }
    }
  }
  __syncthreads();
#undef RED_ST
#undef RED_ADD

  // ---- normalize + coalesced final store --------------------------------
  {
    const int row = t >> 4;
    const int c4  = t & 15;
    const float* p = smem + row * RSTR;
    const float il = 1.f / p[64];
    float4 v = *(const float4*)(p + c4 * 4);
    v.x *= il; v.y *= il; v.z *= il; v.w *= il;
    ((float4*)out)[(size_t)(i0 + row) * 64 + h * 16 + c4] = v;
  }
}

extern "C" void kernel_launch(void* const* d_in, const int* in_sizes, int n_in,
                              void* d_out, int out_size, void* d_ws, size_t ws_size,
                              hipStream_t stream) {
  const float* x   = (const float*)d_in[0];
  const float* W   = (const float*)d_in[1];
  const float* a   = (const float*)d_in[2];
  const int*   adj = (const int*)d_in[3];
  float* out = (float*)d_out;

  float* ws    = (float*)d_ws;
  short* xtB   = (short*)ws;                                // H*N*64 bf16 = 2 MB
  float* src   = ws + 524288;                               // H*N
  float* dst   = src + HEADS * N;                           // H*N
  unsigned* mb = (unsigned*)(dst + HEADS * N);              // N*128 u32 = 2 MB

  k_prep<<<dim3(512 + N * N / 8 / 256), 256, 0, stream>>>(x, W, a, adj, xtB, src, dst,
                                                          (unsigned char*)mb);
  k_flash<<<dim3(N / 32, HEADS), 512, 0, stream>>>(mb, src, dst, xtB, out);
}